// Round 1
// baseline (358.735 us; speedup 1.0000x reference)
//
#include <hip/hip_runtime.h>
#include <math.h>

#define N_NODES 512
#define DIM 128
#define NANCH 192
#define G3 384           // 3*DIM gate width
#define FOUT 47
#define DBINS 21

__device__ __forceinline__ float sigmoidf_(float v) {
    return 1.f / (1.f + __expf(-v));
}

// ---------------- Kernel 1: features, smoothing+softmax abnormal, tpos ----------------
__global__ __launch_bounds__(128) void prep_kernel(
    const float* __restrict__ emb, const float* __restrict__ tpin,
    const float* __restrict__ npred, const float* __restrict__ alp,
    const float* __restrict__ skern,
    float* __restrict__ x, float* __restrict__ abnormal, float* __restrict__ tpos)
{
    int n = blockIdx.x;      // 0..511
    int d = threadIdx.x;     // 0..127
    float tv = tpin[n];
    float freq = 10.f * (float)d / 127.f;
    x[n * DIM + d] = emb[n * DIM + d] + 0.05f * __sinf(tv * freq);
    if (d == 0) {
        tpos[n] = tv * alp[0];
        float sc[5];
        #pragma unroll
        for (int c = 0; c < 5; ++c) {
            float acc = 0.f;
            #pragma unroll
            for (int k = 0; k < 5; ++k) {
                int r = n + k - 2;
                if (r >= 0 && r < N_NODES) acc += skern[k] * npred[r * 5 + c];
            }
            sc[c] = acc;
        }
        float m = sc[0];
        #pragma unroll
        for (int c = 1; c < 5; ++c) m = fmaxf(m, sc[c]);
        float sum = 0.f;
        #pragma unroll
        for (int c = 0; c < 5; ++c) sum += __expf(sc[c] - m);
        abnormal[n] = __expf(sc[0] - m) / sum;
    }
}

// ---------------- Kernel 2: xW = x @ Wih^T + bih for all 6 (scale,dir) ----------------
// grid: 6*32 blocks (sd, node-group of 16), block 384 threads (one output gate each)
__global__ __launch_bounds__(384) void xw_gemm_kernel(
    const float* __restrict__ x, const float* __restrict__ Wih,
    const float* __restrict__ bih, float* __restrict__ xW)
{
    int blk = blockIdx.x;
    int sd = blk >> 5;         // 0..5
    int ng = blk & 31;         // 0..31
    int tid = threadIdx.x;     // 0..383
    __shared__ __align__(16) float xs[16][DIM];
    for (int idx = tid; idx < 16 * DIM; idx += 384) {
        int m = idx >> 7, k = idx & 127;
        xs[m][k] = x[(ng * 16 + m) * DIM + k];
    }
    __syncthreads();
    float acc[16];
    float b = bih[sd * G3 + tid];
    #pragma unroll
    for (int m = 0; m < 16; ++m) acc[m] = b;
    const float* wrow = Wih + ((size_t)sd * G3 + tid) * DIM;
    for (int k = 0; k < DIM; k += 4) {
        float4 w4 = *(const float4*)(wrow + k);
        #pragma unroll
        for (int m = 0; m < 16; ++m) {
            acc[m] = fmaf(w4.x, xs[m][k + 0], acc[m]);
            acc[m] = fmaf(w4.y, xs[m][k + 1], acc[m]);
            acc[m] = fmaf(w4.z, xs[m][k + 2], acc[m]);
            acc[m] = fmaf(w4.w, xs[m][k + 3], acc[m]);
        }
    }
    #pragma unroll
    for (int m = 0; m < 16; ++m)
        xW[((size_t)sd * N_NODES + ng * 16 + m) * G3 + tid] = acc[m];
}

// ---------------- Kernel 3: membership lists + H=1 abnormal BiGRU ----------------
// grid: 192 blocks (one wave per anchor)
__global__ __launch_bounds__(64) void membership_abn_kernel(
    const float* __restrict__ tpos, const float* __restrict__ anchors,
    const float* __restrict__ abnormal,
    const float* __restrict__ aWih, const float* __restrict__ aWhh,
    const float* __restrict__ abih, const float* __restrict__ abhh,
    int* __restrict__ members, int* __restrict__ lens, float* __restrict__ abn_res)
{
    int a = blockIdx.x;
    int lane = threadIdx.x;   // 0..63
    float s0 = anchors[a * 2 + 0];
    float e0 = anchors[a * 2 + 1];
    __shared__ int memloc[N_NODES];
    int count = 0;
    for (int c = 0; c < N_NODES / 64; ++c) {
        int node = c * 64 + lane;
        float tp = tpos[node];
        bool in = (tp >= s0) && (tp <= e0);
        unsigned long long m = __ballot(in);
        if (in) {
            int pos = count + __popcll(m & ((1ull << lane) - 1ull));
            members[a * N_NODES + pos] = node;
            memloc[pos] = node;
        }
        count += __popcll(m);
    }
    if (lane == 0) lens[a] = count;
    __syncthreads();
    // abnormal GRU (H=1): lane 0 forward, lane 1 backward
    int sc = a >> 6;
    float h = 0.f;
    if (lane < 2) {
        int sd = sc * 2 + lane;
        float wi0 = aWih[sd * 3 + 0], wi1 = aWih[sd * 3 + 1], wi2 = aWih[sd * 3 + 2];
        float wh0 = aWhh[sd * 3 + 0], wh1 = aWhh[sd * 3 + 1], wh2 = aWhh[sd * 3 + 2];
        float bi0 = abih[sd * 3 + 0], bi1 = abih[sd * 3 + 1], bi2 = abih[sd * 3 + 2];
        float bh0 = abhh[sd * 3 + 0], bh1 = abhh[sd * 3 + 1], bh2 = abhh[sd * 3 + 2];
        for (int t = 0; t < count; ++t) {
            int idx = lane ? (count - 1 - t) : t;
            float xv = abnormal[memloc[idx]];
            float r = sigmoidf_(fmaf(wi0, xv, bi0) + fmaf(wh0, h, bh0));
            float z = sigmoidf_(fmaf(wi1, xv, bi1) + fmaf(wh1, h, bh1));
            float nv = tanhf(fmaf(wi2, xv, bi2) + r * fmaf(wh2, h, bh2));
            h = (1.f - z) * nv + z * h;
        }
    }
    float hb = __shfl(h, 1);
    if (lane == 0) abn_res[a] = 0.5f * (h + hb);
}

// ---------------- Kernel 4: H=128 feature GRU recurrence ----------------
// grid: 384 blocks = (anchor, dir). block 384 threads; thread i owns Whh row i in VGPRs.
__global__ __launch_bounds__(384, 1) void gru_feat_kernel(
    const float* __restrict__ xW, const float* __restrict__ Whh,
    const float* __restrict__ bhh, const int* __restrict__ members,
    const int* __restrict__ lens, float* __restrict__ feat_out)
{
    int b = blockIdx.x;
    int a = b >> 1;
    int dir = b & 1;
    int s = a >> 6;
    int sd = s * 2 + dir;
    int tid = threadIdx.x;   // 0..383 (gate row)

    // preload this thread's Whh row into registers
    const float* wrow = Whh + ((size_t)sd * G3 + tid) * DIM;
    float w[DIM];
    #pragma unroll
    for (int k = 0; k < DIM; k += 4) {
        float4 t4 = *(const float4*)(wrow + k);
        w[k + 0] = t4.x; w[k + 1] = t4.y; w[k + 2] = t4.z; w[k + 3] = t4.w;
    }
    float bh = bhh[sd * G3 + tid];
    const float* xWp = xW + (size_t)sd * N_NODES * G3;
    const int* mem = members + a * N_NODES;
    int len = lens[a];

    __shared__ __align__(16) float h_lds[DIM];
    __shared__ float r_lds[DIM];
    __shared__ float z_lds[DIM];
    if (tid < DIM) h_lds[tid] = 0.f;
    __syncthreads();

    for (int t = 0; t < len; ++t) {
        int idx = dir ? (len - 1 - t) : t;
        int node = mem[idx];
        float gi = xWp[node * G3 + tid];   // issued early, consumed after dot
        float acc = bh;
        const float4* h4 = (const float4*)h_lds;
        #pragma unroll
        for (int k4 = 0; k4 < DIM / 4; ++k4) {
            float4 hv = h4[k4];            // wave-uniform broadcast read
            acc = fmaf(w[4 * k4 + 0], hv.x, acc);
            acc = fmaf(w[4 * k4 + 1], hv.y, acc);
            acc = fmaf(w[4 * k4 + 2], hv.z, acc);
            acc = fmaf(w[4 * k4 + 3], hv.w, acc);
        }
        if (tid < DIM) {
            r_lds[tid] = sigmoidf_(gi + acc);
        } else if (tid < 2 * DIM) {
            z_lds[tid - DIM] = sigmoidf_(gi + acc);
        }
        __syncthreads();
        if (tid >= 2 * DIM) {
            int j = tid - 2 * DIM;
            float r = r_lds[j];
            float nv = tanhf(gi + r * acc);
            float z = z_lds[j];
            h_lds[j] = (1.f - z) * nv + z * h_lds[j];
        }
        __syncthreads();
    }
    if (tid < DIM) feat_out[a * 256 + dir * DIM + tid] = h_lds[tid];
}

// ---------------- Kernel 5: per-anchor MLP head + boundary refinement ----------------
__global__ __launch_bounds__(256) void head_kernel(
    const float* __restrict__ feat, const float* __restrict__ abn_res,
    const float* __restrict__ anchors, const float* __restrict__ alp,
    const float* __restrict__ W1, const float* __restrict__ b1,
    const float* __restrict__ W2, const float* __restrict__ b2,
    const float* __restrict__ W3, const float* __restrict__ b3,
    const float* __restrict__ sw, const float* __restrict__ ew,
    float* __restrict__ out)
{
    int a = blockIdx.x;
    int tid = threadIdx.x;   // 0..255
    int s = a >> 6;
    __shared__ float sf[259];
    __shared__ float h1[256];
    __shared__ float h2[256];
    __shared__ float o[FOUT];
    float al = alp[0];
    float st = anchors[a * 2 + 0];
    float en = anchors[a * 2 + 1];
    sf[tid] = feat[a * 256 + tid];
    if (tid == 0) {
        sf[256] = abn_res[a];
        sf[257] = (st + en) * 0.5f / al;
        sf[258] = (en - st) / al;
    }
    __syncthreads();

    const float* w1 = W1 + (size_t)s * 259 * 256;
    float acc = b1[s * 256 + tid];
    for (int j = 0; j < 259; ++j) acc = fmaf(sf[j], w1[j * 256 + tid], acc);
    h1[tid] = fmaxf(acc, 0.f);
    __syncthreads();

    const float* w2 = W2 + (size_t)s * 256 * 256;
    acc = b2[s * 256 + tid];
    for (int j = 0; j < 256; ++j) acc = fmaf(h1[j], w2[j * 256 + tid], acc);
    h2[tid] = fmaxf(acc, 0.f);
    __syncthreads();

    if (tid < FOUT) {
        const float* w3 = W3 + (size_t)s * 256 * FOUT;
        acc = b3[s * FOUT + tid];
        for (int j = 0; j < 256; ++j) acc = fmaf(h2[j], w3[j * FOUT + tid], acc);
        o[tid] = acc;
    }
    __syncthreads();

    if (tid < 2) {  // tid 0: start offset, tid 1: end offset
        const float* lw = (tid == 0) ? (sw + s * DBINS) : (ew + s * DBINS);
        const float* sl = o + tid * DBINS;
        float m = sl[0];
        for (int j = 1; j < DBINS; ++j) m = fmaxf(m, sl[j]);
        float sum = 0.f, dot = 0.f;
        for (int j = 0; j < DBINS; ++j) {
            float e = __expf(sl[j] - m);
            sum += e;
            dot = fmaf(e, lw[j], dot);
        }
        float off = dot / sum;
        float base = (tid == 0) ? st : en;
        out[a * 2 + tid] = fminf(fmaxf(base + off, 0.f), al);
    }
    if (tid == 42) out[2 * NANCH + a] = o[42];                       // conf
    if (tid >= 43 && tid < FOUT) out[3 * NANCH + a * 4 + (tid - 43)] = o[tid];  // cls
}

extern "C" void kernel_launch(void* const* d_in, const int* in_sizes, int n_in,
                              void* d_out, int out_size, void* d_ws, size_t ws_size,
                              hipStream_t stream) {
    const float* emb   = (const float*)d_in[0];
    const float* tpin  = (const float*)d_in[1];
    const float* npred = (const float*)d_in[2];
    const float* alp   = (const float*)d_in[3];
    const float* anch  = (const float*)d_in[4];
    const float* skern = (const float*)d_in[5];
    const float* fWih  = (const float*)d_in[6];
    const float* fWhh  = (const float*)d_in[7];
    const float* fbih  = (const float*)d_in[8];
    const float* fbhh  = (const float*)d_in[9];
    const float* aWih  = (const float*)d_in[10];
    const float* aWhh  = (const float*)d_in[11];
    const float* abih  = (const float*)d_in[12];
    const float* abhh  = (const float*)d_in[13];
    const float* sw    = (const float*)d_in[14];
    const float* ew    = (const float*)d_in[15];
    const float* W1    = (const float*)d_in[16];
    const float* b1    = (const float*)d_in[17];
    const float* W2    = (const float*)d_in[18];
    const float* b2    = (const float*)d_in[19];
    const float* W3    = (const float*)d_in[20];
    const float* b3    = (const float*)d_in[21];

    float* ws = (float*)d_ws;
    float* x        = ws;                      // 512*128          = 65536
    float* xW       = ws + 65536;              // 6*512*384        = 1179648
    float* abnormal = ws + 1245184;            // 512
    float* tpos     = ws + 1245696;            // 512
    float* abn_res  = ws + 1246208;            // 192 (+pad)
    float* feat     = ws + 1246464;            // 192*256          = 49152
    int*   members  = (int*)(ws + 1295616);    // 192*512 ints     = 98304
    int*   lens     = (int*)(ws + 1393920);    // 192 ints
    float* outp     = (float*)d_out;

    prep_kernel<<<N_NODES, DIM, 0, stream>>>(emb, tpin, npred, alp, skern, x, abnormal, tpos);
    xw_gemm_kernel<<<6 * 32, 384, 0, stream>>>(x, fWih, fbih, xW);
    membership_abn_kernel<<<NANCH, 64, 0, stream>>>(tpos, anch, abnormal, aWih, aWhh, abih, abhh,
                                                    members, lens, abn_res);
    gru_feat_kernel<<<2 * NANCH, 384, 0, stream>>>(xW, fWhh, fbhh, members, lens, feat);
    head_kernel<<<NANCH, 256, 0, stream>>>(feat, abn_res, anch, alp,
                                           W1, b1, W2, b2, W3, b3, sw, ew, outp);
}

// Round 2
// 271.129 us; speedup vs baseline: 1.3231x; 1.3231x over previous
//
#include <hip/hip_runtime.h>
#include <math.h>

#define N_NODES 512
#define DIM 128
#define NANCH 192
#define G3 384           // 3*DIM gate width
#define FOUT 47
#define DBINS 21

__device__ __forceinline__ float fast_sigmoid(float x) {
    return __builtin_amdgcn_rcpf(1.f + __expf(-x));
}
__device__ __forceinline__ float fast_tanh(float x) {
    return 1.f - 2.f * __builtin_amdgcn_rcpf(1.f + __expf(2.f * x));
}

// ---------------- Kernel 1: features, smoothing+softmax abnormal, tpos ----------------
__global__ __launch_bounds__(128) void prep_kernel(
    const float* __restrict__ emb, const float* __restrict__ tpin,
    const float* __restrict__ npred, const float* __restrict__ alp,
    const float* __restrict__ skern,
    float* __restrict__ x, float* __restrict__ abnormal, float* __restrict__ tpos)
{
    int n = blockIdx.x;      // 0..511
    int d = threadIdx.x;     // 0..127
    float tv = tpin[n];
    float freq = 10.f * (float)d / 127.f;
    x[n * DIM + d] = emb[n * DIM + d] + 0.05f * __sinf(tv * freq);
    if (d == 0) {
        tpos[n] = tv * alp[0];
        float sc[5];
        #pragma unroll
        for (int c = 0; c < 5; ++c) {
            float acc = 0.f;
            #pragma unroll
            for (int k = 0; k < 5; ++k) {
                int r = n + k - 2;
                if (r >= 0 && r < N_NODES) acc += skern[k] * npred[r * 5 + c];
            }
            sc[c] = acc;
        }
        float m = sc[0];
        #pragma unroll
        for (int c = 1; c < 5; ++c) m = fmaxf(m, sc[c]);
        float sum = 0.f;
        #pragma unroll
        for (int c = 0; c < 5; ++c) sum += __expf(sc[c] - m);
        abnormal[n] = __expf(sc[0] - m) / sum;
    }
}

// ---------------- Kernel 2: xW = x @ Wih^T + bih for all 6 (scale,dir) ----------------
__global__ __launch_bounds__(384) void xw_gemm_kernel(
    const float* __restrict__ x, const float* __restrict__ Wih,
    const float* __restrict__ bih, float* __restrict__ xW)
{
    int blk = blockIdx.x;
    int sd = blk >> 5;         // 0..5
    int ng = blk & 31;         // 0..31
    int tid = threadIdx.x;     // 0..383
    __shared__ __align__(16) float xs[16][DIM];
    for (int idx = tid; idx < 16 * DIM; idx += 384) {
        int m = idx >> 7, k = idx & 127;
        xs[m][k] = x[(ng * 16 + m) * DIM + k];
    }
    __syncthreads();
    float acc[16];
    float b = bih[sd * G3 + tid];
    #pragma unroll
    for (int m = 0; m < 16; ++m) acc[m] = b;
    const float* wrow = Wih + ((size_t)sd * G3 + tid) * DIM;
    for (int k = 0; k < DIM; k += 4) {
        float4 w4 = *(const float4*)(wrow + k);
        #pragma unroll
        for (int m = 0; m < 16; ++m) {
            float4 xv = *(const float4*)&xs[m][k];   // wave-uniform b128 broadcast
            acc[m] = fmaf(w4.x, xv.x, acc[m]);
            acc[m] = fmaf(w4.y, xv.y, acc[m]);
            acc[m] = fmaf(w4.z, xv.z, acc[m]);
            acc[m] = fmaf(w4.w, xv.w, acc[m]);
        }
    }
    #pragma unroll
    for (int m = 0; m < 16; ++m)
        xW[((size_t)sd * N_NODES + ng * 16 + m) * G3 + tid] = acc[m];
}

// ---------------- Kernel 3: membership lists + H=1 abnormal BiGRU ----------------
__global__ __launch_bounds__(64) void membership_abn_kernel(
    const float* __restrict__ tpos, const float* __restrict__ anchors,
    const float* __restrict__ abnormal,
    const float* __restrict__ aWih, const float* __restrict__ aWhh,
    const float* __restrict__ abih, const float* __restrict__ abhh,
    int* __restrict__ members, int* __restrict__ lens, float* __restrict__ abn_res)
{
    int a = blockIdx.x;
    int lane = threadIdx.x;   // 0..63
    float s0 = anchors[a * 2 + 0];
    float e0 = anchors[a * 2 + 1];
    __shared__ int memloc[N_NODES];
    int count = 0;
    for (int c = 0; c < N_NODES / 64; ++c) {
        int node = c * 64 + lane;
        float tp = tpos[node];
        bool in = (tp >= s0) && (tp <= e0);
        unsigned long long m = __ballot(in);
        if (in) {
            int pos = count + __popcll(m & ((1ull << lane) - 1ull));
            members[a * N_NODES + pos] = node;
            memloc[pos] = node;
        }
        count += __popcll(m);
    }
    if (lane == 0) lens[a] = count;
    __syncthreads();
    int sc = a >> 6;
    float h = 0.f;
    if (lane < 2) {
        int sd = sc * 2 + lane;
        float wi0 = aWih[sd * 3 + 0], wi1 = aWih[sd * 3 + 1], wi2 = aWih[sd * 3 + 2];
        float wh0 = aWhh[sd * 3 + 0], wh1 = aWhh[sd * 3 + 1], wh2 = aWhh[sd * 3 + 2];
        float bi0 = abih[sd * 3 + 0], bi1 = abih[sd * 3 + 1], bi2 = abih[sd * 3 + 2];
        float bh0 = abhh[sd * 3 + 0], bh1 = abhh[sd * 3 + 1], bh2 = abhh[sd * 3 + 2];
        for (int t = 0; t < count; ++t) {
            int idx = lane ? (count - 1 - t) : t;
            float xv = abnormal[memloc[idx]];
            float r = fast_sigmoid(fmaf(wi0, xv, bi0) + fmaf(wh0, h, bh0));
            float z = fast_sigmoid(fmaf(wi1, xv, bi1) + fmaf(wh1, h, bh1));
            float nv = fast_tanh(fmaf(wi2, xv, bi2) + r * fmaf(wh2, h, bh2));
            h = (1.f - z) * nv + z * h;
        }
    }
    float hb = __shfl(h, 1);
    if (lane == 0) abn_res[a] = 0.5f * (h + hb);
}

// ---------------- Kernel 4: H=128 feature GRU recurrence ----------------
// grid: 384 blocks = (anchor, dir). 512 threads: thread = (j = t>>2, s = t&3).
// Thread holds 3x32 Whh weights in VGPRs; quad shfl-reduce; 1 barrier/step.
__global__ __launch_bounds__(512, 2) void gru_feat_kernel(
    const float* __restrict__ xW, const float* __restrict__ Whh,
    const float* __restrict__ bhh, const int* __restrict__ members,
    const int* __restrict__ lens, float* __restrict__ feat_out)
{
    int b = blockIdx.x;
    int a = b >> 1;
    int dir = b & 1;
    int s3 = a >> 6;           // scale
    int sd = s3 * 2 + dir;
    int t0 = threadIdx.x;      // 0..511
    int j  = t0 >> 2;          // 0..127 : owned h element
    int s  = t0 & 3;           // 0..3   : 32-wide K slice

    // --- preload Whh slices into registers (96 floats/thread) ---
    float wr[32], wz[32], wn[32];
    {
        const float* base = Whh + ((size_t)sd * G3) * DIM;
        const float* pr = base + (size_t)(j        ) * DIM + s * 32;
        const float* pz = base + (size_t)(j + DIM  ) * DIM + s * 32;
        const float* pn = base + (size_t)(j + 2*DIM) * DIM + s * 32;
        #pragma unroll
        for (int q = 0; q < 8; ++q) {
            float4 v = *(const float4*)(pr + 4 * q);
            wr[4*q+0]=v.x; wr[4*q+1]=v.y; wr[4*q+2]=v.z; wr[4*q+3]=v.w;
        }
        #pragma unroll
        for (int q = 0; q < 8; ++q) {
            float4 v = *(const float4*)(pz + 4 * q);
            wz[4*q+0]=v.x; wz[4*q+1]=v.y; wz[4*q+2]=v.z; wz[4*q+3]=v.w;
        }
        #pragma unroll
        for (int q = 0; q < 8; ++q) {
            float4 v = *(const float4*)(pn + 4 * q);
            wn[4*q+0]=v.x; wn[4*q+1]=v.y; wn[4*q+2]=v.z; wn[4*q+3]=v.w;
        }
    }
    float bhr = bhh[sd * G3 + j];
    float bhz = bhh[sd * G3 + DIM + j];
    float bhn = bhh[sd * G3 + 2 * DIM + j];

    const float* xWp = xW + (size_t)sd * N_NODES * G3;
    const int* mem = members + a * N_NODES;
    int len = lens[a];

    // h ping-pong, slice-padded: slice s at [buf][s][0..31], stride 36 floats
    __shared__ __align__(16) float hbuf[2][4][36];
    for (int i = t0; i < 2 * 4 * 36; i += 512) ((float*)hbuf)[i] = 0.f;
    __syncthreads();

    // prefetch gi for step 0
    int node = (len > 0) ? mem[dir ? (len - 1) : 0] : 0;
    float gr = xWp[(size_t)node * G3 + j];
    float gz = xWp[(size_t)node * G3 + DIM + j];
    float gn = xWp[(size_t)node * G3 + 2 * DIM + j];

    int cur = 0;
    for (int t = 0; t < len; ++t) {
        // prefetch next step's gi (overlaps this step's compute + barrier)
        float gr_n = 0.f, gz_n = 0.f, gn_n = 0.f;
        if (t + 1 < len) {
            int nn = mem[dir ? (len - 2 - t) : (t + 1)];
            gr_n = xWp[(size_t)nn * G3 + j];
            gz_n = xWp[(size_t)nn * G3 + DIM + j];
            gn_n = xWp[(size_t)nn * G3 + 2 * DIM + j];
        }
        // partial dots over this thread's 32-wide K slice
        float ar = 0.f, az = 0.f, an_ = 0.f;
        const float4* hp = (const float4*)(&hbuf[cur][s][0]);
        #pragma unroll
        for (int q = 0; q < 8; ++q) {
            float4 hv = hp[q];
            ar = fmaf(wr[4*q+0], hv.x, ar); ar = fmaf(wr[4*q+1], hv.y, ar);
            ar = fmaf(wr[4*q+2], hv.z, ar); ar = fmaf(wr[4*q+3], hv.w, ar);
            az = fmaf(wz[4*q+0], hv.x, az); az = fmaf(wz[4*q+1], hv.y, az);
            az = fmaf(wz[4*q+2], hv.z, az); az = fmaf(wz[4*q+3], hv.w, az);
            an_ = fmaf(wn[4*q+0], hv.x, an_); an_ = fmaf(wn[4*q+1], hv.y, an_);
            an_ = fmaf(wn[4*q+2], hv.z, an_); an_ = fmaf(wn[4*q+3], hv.w, an_);
        }
        // quad reduction (lanes j*4+0..3 adjacent in wave)
        ar  += __shfl_xor(ar, 1);  ar  += __shfl_xor(ar, 2);
        az  += __shfl_xor(az, 1);  az  += __shfl_xor(az, 2);
        an_ += __shfl_xor(an_, 1); an_ += __shfl_xor(an_, 2);

        float r  = fast_sigmoid(gr + ar + bhr);
        float z  = fast_sigmoid(gz + az + bhz);
        float nv = fast_tanh(gn + r * (an_ + bhn));
        float hj = hbuf[cur][j >> 5][j & 31];
        float hnew = (1.f - z) * nv + z * hj;
        if (s == 0) hbuf[cur ^ 1][j >> 5][j & 31] = hnew;
        __syncthreads();
        cur ^= 1;
        gr = gr_n; gz = gz_n; gn = gn_n;
    }
    if (s == 0) feat_out[a * 256 + dir * DIM + j] = hbuf[cur][j >> 5][j & 31];
}

// ---------------- Kernel 5: per-anchor MLP head + boundary refinement ----------------
__global__ __launch_bounds__(256) void head_kernel(
    const float* __restrict__ feat, const float* __restrict__ abn_res,
    const float* __restrict__ anchors, const float* __restrict__ alp,
    const float* __restrict__ W1, const float* __restrict__ b1,
    const float* __restrict__ W2, const float* __restrict__ b2,
    const float* __restrict__ W3, const float* __restrict__ b3,
    const float* __restrict__ sw, const float* __restrict__ ew,
    float* __restrict__ out)
{
    int a = blockIdx.x;
    int tid = threadIdx.x;   // 0..255
    int s = a >> 6;
    __shared__ float sf[259];
    __shared__ float h1[256];
    __shared__ float h2[256];
    __shared__ float o[FOUT];
    float al = alp[0];
    float st = anchors[a * 2 + 0];
    float en = anchors[a * 2 + 1];
    sf[tid] = feat[a * 256 + tid];
    if (tid == 0) {
        sf[256] = abn_res[a];
        sf[257] = (st + en) * 0.5f / al;
        sf[258] = (en - st) / al;
    }
    __syncthreads();

    const float* w1 = W1 + (size_t)s * 259 * 256;
    float acc = b1[s * 256 + tid];
    for (int jj = 0; jj < 259; ++jj) acc = fmaf(sf[jj], w1[jj * 256 + tid], acc);
    h1[tid] = fmaxf(acc, 0.f);
    __syncthreads();

    const float* w2 = W2 + (size_t)s * 256 * 256;
    acc = b2[s * 256 + tid];
    for (int jj = 0; jj < 256; ++jj) acc = fmaf(h1[jj], w2[jj * 256 + tid], acc);
    h2[tid] = fmaxf(acc, 0.f);
    __syncthreads();

    if (tid < FOUT) {
        const float* w3 = W3 + (size_t)s * 256 * FOUT;
        acc = b3[s * FOUT + tid];
        for (int jj = 0; jj < 256; ++jj) acc = fmaf(h2[jj], w3[jj * FOUT + tid], acc);
        o[tid] = acc;
    }
    __syncthreads();

    if (tid < 2) {  // tid 0: start offset, tid 1: end offset
        const float* lw = (tid == 0) ? (sw + s * DBINS) : (ew + s * DBINS);
        const float* sl = o + tid * DBINS;
        float m = sl[0];
        for (int jj = 1; jj < DBINS; ++jj) m = fmaxf(m, sl[jj]);
        float sum = 0.f, dot = 0.f;
        for (int jj = 0; jj < DBINS; ++jj) {
            float e = __expf(sl[jj] - m);
            sum += e;
            dot = fmaf(e, lw[jj], dot);
        }
        float off = dot / sum;
        float base = (tid == 0) ? st : en;
        out[a * 2 + tid] = fminf(fmaxf(base + off, 0.f), al);
    }
    if (tid == 42) out[2 * NANCH + a] = o[42];                       // conf
    if (tid >= 43 && tid < FOUT) out[3 * NANCH + a * 4 + (tid - 43)] = o[tid];  // cls
}

extern "C" void kernel_launch(void* const* d_in, const int* in_sizes, int n_in,
                              void* d_out, int out_size, void* d_ws, size_t ws_size,
                              hipStream_t stream) {
    const float* emb   = (const float*)d_in[0];
    const float* tpin  = (const float*)d_in[1];
    const float* npred = (const float*)d_in[2];
    const float* alp   = (const float*)d_in[3];
    const float* anch  = (const float*)d_in[4];
    const float* skern = (const float*)d_in[5];
    const float* fWih  = (const float*)d_in[6];
    const float* fWhh  = (const float*)d_in[7];
    const float* fbih  = (const float*)d_in[8];
    const float* fbhh  = (const float*)d_in[9];
    const float* aWih  = (const float*)d_in[10];
    const float* aWhh  = (const float*)d_in[11];
    const float* abih  = (const float*)d_in[12];
    const float* abhh  = (const float*)d_in[13];
    const float* sw    = (const float*)d_in[14];
    const float* ew    = (const float*)d_in[15];
    const float* W1    = (const float*)d_in[16];
    const float* b1    = (const float*)d_in[17];
    const float* W2    = (const float*)d_in[18];
    const float* b2    = (const float*)d_in[19];
    const float* W3    = (const float*)d_in[20];
    const float* b3    = (const float*)d_in[21];

    float* ws = (float*)d_ws;
    float* x        = ws;                      // 512*128          = 65536
    float* xW       = ws + 65536;              // 6*512*384        = 1179648
    float* abnormal = ws + 1245184;            // 512
    float* tpos     = ws + 1245696;            // 512
    float* abn_res  = ws + 1246208;            // 192 (+pad)
    float* feat     = ws + 1246464;            // 192*256          = 49152
    int*   members  = (int*)(ws + 1295616);    // 192*512 ints     = 98304
    int*   lens     = (int*)(ws + 1393920);    // 192 ints
    float* outp     = (float*)d_out;

    prep_kernel<<<N_NODES, DIM, 0, stream>>>(emb, tpin, npred, alp, skern, x, abnormal, tpos);
    xw_gemm_kernel<<<6 * 32, 384, 0, stream>>>(x, fWih, fbih, xW);
    membership_abn_kernel<<<NANCH, 64, 0, stream>>>(tpos, anch, abnormal, aWih, aWhh, abih, abhh,
                                                    members, lens, abn_res);
    gru_feat_kernel<<<2 * NANCH, 512, 0, stream>>>(xW, fWhh, fbhh, members, lens, feat);
    head_kernel<<<NANCH, 256, 0, stream>>>(feat, abn_res, anch, alp,
                                           W1, b1, W2, b2, W3, b3, sw, ew, outp);
}